// Round 12
// baseline (65.049 us; speedup 1.0000x reference)
//
#include <hip/hip_runtime.h>

// DifferenceCost, two-pass, fragment-major workspace:
//  Pass A: fp32 [b][c][h][w] -> bf16 MFMA-fragment layout
//          frag[b][row][qtile(12)][kc(4)][lane(64)] (16B per lane), plus
//          per-pixel sum-of-squares planes R2/T2 (on bf16-rounded values).
//  Pass B (corrcost12): block = (b, h, W-half). 6 waves, wave = one wt for
//          ALL 9 i. Per row: 28KB contiguous B-halo DMA-staged once per block
//          (double-buffered, 1 barrier/row); A frags in regs (read once).
//          Traffic ~330MB total vs 1.16GB in R11. cost=sqrt(max(R2+T2-2X,0)).
// Falls back to round-3 single-kernel path if ws too small.

#define B_N 4
#define C_N 128
#define H_N 96
#define W_N 192
#define TPLANE (H_N * W_N)                 // 18432
#define CPLANE ((size_t)C_N * TPLANE)

#define FRAG_ROW_SZ ((size_t)12 * 4 * 1024)          // 49152 B per (b,row)
#define BF_SZ   ((size_t)B_N * H_N * FRAG_ROW_SZ)    // 18,874,368
#define REFF_OFF ((size_t)0)
#define TGTF_OFF BF_SZ
#define SQ_SZ   ((size_t)B_N * TPLANE * 4)
#define R2_OFF  (2 * BF_SZ)
#define T2_OFF  (R2_OFF + SQ_SZ)
#define WS_NEED (T2_OFF + SQ_SZ)                     // 38,338,560 B

using f32x4 = __attribute__((ext_vector_type(4))) float;
using s16x8 = __attribute__((ext_vector_type(8))) short;

typedef const __attribute__((address_space(1))) void* gas1_t;
typedef __attribute__((address_space(3))) void* las3_t;
#define GLL16(gp, lp) __builtin_amdgcn_global_load_lds((gas1_t)(gp), (las3_t)(lp), 16, 0, 0)

__device__ __forceinline__ short f2bf(float x) {
    unsigned u = __builtin_bit_cast(unsigned, x);
    u = (u + 0x7fffu + ((u >> 16) & 1u)) >> 16;   // RNE; inputs finite
    return (short)(unsigned short)u;
}
__device__ __forceinline__ float bf2f(short s) {
    return __builtin_bit_cast(float, ((unsigned)(unsigned short)s) << 16);
}

// ---------------- Pass A: convert + fragment-major store + squared sums ----
__global__ __launch_bounds__(256, 4)
void convert_frag(const float* __restrict__ ref, const float* __restrict__ tgt,
                  unsigned char* __restrict__ ws)
{
    __shared__ unsigned int l32[64][65];   // [w][c-pair], stride 65 -> no conflicts

    const int tid = threadIdx.x;
    // bijective XCD chunk swizzle, (b,h)-major order shared with pass B
    const int bid = blockIdx.x;
    const int u2  = (bid & 7) * 144 + (bid >> 3);   // 1152 = 8 x 144
    const int wc  = u2 % 3;               // which 64-w chunk
    const int h   = (u2 / 3) % H_N;
    const int b   = u2 / (3 * H_N);
    const int w0  = wc * 64;
    const int isT = blockIdx.y;

    const float* src = (isT ? tgt : ref) + (size_t)b * CPLANE + h * W_N + w0;
    unsigned char* dstF = ws + (isT ? TGTF_OFF : REFF_OFF);
    float* sq = (float*)(ws + (isT ? T2_OFF : R2_OFF));

    // phase 1: coalesced fp32 read, convert, pack pairs into LDS
    const int w  = tid & 63;
    const int cq = tid >> 6;
#pragma unroll
    for (int batch = 0; batch < 16; ++batch) {
        int cp = batch * 4 + cq;
        float v0 = src[(size_t)(2 * cp + 0) * TPLANE + w];
        float v1 = src[(size_t)(2 * cp + 1) * TPLANE + w];
        unsigned u = ((unsigned)(unsigned short)f2bf(v0))
                   | ((unsigned)(unsigned short)f2bf(v1) << 16);
        l32[w][cp] = u;
    }
    __syncthreads();

    // phase 2: fragment-major store; each wave-iter writes 1KB contiguous.
#pragma unroll
    for (int it = 0; it < 4; ++it) {
        int idx   = it * 256 + tid;        // 0..1023
        int lane2 = idx & 63;
        int kc    = (idx >> 6) & 3;
        int qt_l  = idx >> 8;              // 0..3
        int w_l   = qt_l * 16 + (lane2 & 15);
        int cp0   = kc * 16 + (lane2 >> 4) * 4;
        uint4 d = make_uint4(l32[w_l][cp0], l32[w_l][cp0 + 1],
                             l32[w_l][cp0 + 2], l32[w_l][cp0 + 3]);
        int qt = wc * 4 + qt_l;
        size_t off = (((size_t)(b * H_N + h) * 12 + qt) * 4 + kc) * 1024
                   + (size_t)lane2 * 16;
        *(uint4*)(dstF + off) = d;
    }

    // phase 3: per-pixel sum of squares (bf16-rounded)
    const int cs = tid & 15;
#pragma unroll
    for (int pass = 0; pass < 4; ++pass) {
        int wr = pass * 16 + (tid >> 4);
        float s = 0.f;
#pragma unroll
        for (int k2 = 0; k2 < 4; ++k2) {
            unsigned u = l32[wr][cs * 4 + k2];
            float lo = __builtin_bit_cast(float, u << 16);
            float hi = __builtin_bit_cast(float, u & 0xffff0000u);
            s = fmaf(lo, lo, fmaf(hi, hi, s));
        }
        s += __shfl_xor(s, 1); s += __shfl_xor(s, 2);
        s += __shfl_xor(s, 4); s += __shfl_xor(s, 8);
        if (cs == 0) sq[(size_t)(b * TPLANE + h * W_N + w0 + wr)] = s;
    }
}

// ---------------- Pass B: block=(b,h,half); 6 waves; 9 rows staged ---------
#define MFMA_B16 __builtin_amdgcn_mfma_f32_16x16x32_bf16

__global__ __launch_bounds__(384)
void corrcost12(const unsigned char* __restrict__ ws, float* __restrict__ out)
{
    __shared__ unsigned char ldsB[2][7 * 4096];   // 2 x 28 KiB B-halo dbuf
    __shared__ float ldsx[6][16][12];             // per-wave extract transpose

    const int tid  = threadIdx.x;
    const int lane = tid & 63;
    const int wv   = tid >> 6;        // 0..5
    const int col  = lane & 15;
    const int grp  = lane >> 4;

    // 768 blocks = 8 XCDs x 96 (bijective); u = (b*96+h)*2 + s  (h-contig/XCD)
    const int bid = blockIdx.x;
    const int u   = (bid & 7) * 96 + (bid >> 3);
    const int s   = u & 1;
    const int bh  = u >> 1;
    const int h   = bh % H_N;
    const int b   = bh / H_N;
    const int bT  = b * TPLANE;

    const int wt  = s * 6 + wv;
    const int w0  = wt * 16;
    const int qt0 = s ? 5 : 0;        // staged halo = qt0..qt0+6 (28KB contig)
    const int qlb = wv - (s ? 0 : 1); // ql = qlb + d
    const bool dok0 = (wt >= 1);
    const bool dok2 = (wt <= 10);

    const unsigned char* tgtF = ws + TGTF_OFF;

    // prologue: stage row(i=0) into buf 0
    {
        const int row0 = h - 4;
        if (row0 >= 0) {
            const unsigned char* fB = tgtF + (size_t)(b * H_N + row0) * FRAG_ROW_SZ
                                    + (size_t)qt0 * 4096;
#pragma unroll
            for (int k = 0; k < 5; ++k) {
                int m = wv + 6 * k;
                if (m < 28)
                    GLL16(fB + (size_t)m * 1024 + (size_t)lane * 16,
                          &ldsB[0][0] + m * 1024);
            }
        }
    }

    // A fragments + R2 (global, overlap with prologue DMA)
    const unsigned char* fA = ws + REFF_OFF
        + ((size_t)(b * H_N + h) * 12 + wt) * 4096 + (size_t)lane * 16;
    const s16x8 A0 = *(const s16x8*)(fA);
    const s16x8 A1 = *(const s16x8*)(fA + 1024);
    const s16x8 A2 = *(const s16x8*)(fA + 2048);
    const s16x8 A3 = *(const s16x8*)(fA + 3072);

    const float* r2p = (const float*)(ws + R2_OFF) + bT + h * W_N + w0;
    const f32x4 r2v = *(const f32x4*)(r2p + grp * 4);

    const float* t2pl = (const float*)(ws + T2_OFF) + bT;
    float* outb0 = out + (size_t)b * 81 * TPLANE + h * W_N + w0;

    for (int i = 0; i < 9; ++i) {
        __syncthreads();   // stage(i) drained (vmcnt), compute(i-1) LDS reads done

        const int row  = h + i - 4;
        const bool rok = (unsigned)row < (unsigned)H_N;   // block-uniform

        // issue stage for row(i+1) into other buffer; lands under compute(i)
        if (i < 8) {
            const int nrow = row + 1;
            if ((unsigned)nrow < (unsigned)H_N) {
                const unsigned char* fB = tgtF + (size_t)(b * H_N + nrow) * FRAG_ROW_SZ
                                        + (size_t)qt0 * 4096;
                unsigned char* lb = &ldsB[(i + 1) & 1][0];
#pragma unroll
                for (int k = 0; k < 5; ++k) {
                    int m = wv + 6 * k;
                    if (m < 28)
                        GLL16(fB + (size_t)m * 1024 + (size_t)lane * 16,
                              lb + m * 1024);
                }
            }
        }

        // ---- compute row i from ldsB[i&1] ----
        f32x4 acc0 = {0.f, 0.f, 0.f, 0.f}, acc1 = acc0, acc2 = acc0;
        float t20 = 0.f, t21 = 0.f, t22 = 0.f;

        if (rok) {
            const float* t2r = t2pl + row * W_N;
            if (dok0) t20 = t2r[(wt - 1) * 16 + col];
            t21 = t2r[wt * 16 + col];
            if (dok2) t22 = t2r[(wt + 1) * 16 + col];

            const unsigned char* sb = &ldsB[i & 1][0] + (size_t)lane * 16;
            if (dok0) {
                const unsigned char* p = sb + (size_t)(qlb + 0) * 4096;
                const s16x8 B0 = *(const s16x8*)(p);
                const s16x8 B1 = *(const s16x8*)(p + 1024);
                const s16x8 B2 = *(const s16x8*)(p + 2048);
                const s16x8 B3 = *(const s16x8*)(p + 3072);
                acc0 = MFMA_B16(A0, B0, acc0, 0, 0, 0);
                acc0 = MFMA_B16(A1, B1, acc0, 0, 0, 0);
                acc0 = MFMA_B16(A2, B2, acc0, 0, 0, 0);
                acc0 = MFMA_B16(A3, B3, acc0, 0, 0, 0);
            }
            {
                const unsigned char* p = sb + (size_t)(qlb + 1) * 4096;
                const s16x8 B0 = *(const s16x8*)(p);
                const s16x8 B1 = *(const s16x8*)(p + 1024);
                const s16x8 B2 = *(const s16x8*)(p + 2048);
                const s16x8 B3 = *(const s16x8*)(p + 3072);
                acc1 = MFMA_B16(A0, B0, acc1, 0, 0, 0);
                acc1 = MFMA_B16(A1, B1, acc1, 0, 0, 0);
                acc1 = MFMA_B16(A2, B2, acc1, 0, 0, 0);
                acc1 = MFMA_B16(A3, B3, acc1, 0, 0, 0);
            }
            if (dok2) {
                const unsigned char* p = sb + (size_t)(qlb + 2) * 4096;
                const s16x8 B0 = *(const s16x8*)(p);
                const s16x8 B1 = *(const s16x8*)(p + 1024);
                const s16x8 B2 = *(const s16x8*)(p + 2048);
                const s16x8 B3 = *(const s16x8*)(p + 3072);
                acc2 = MFMA_B16(A0, B0, acc2, 0, 0, 0);
                acc2 = MFMA_B16(A1, B1, acc2, 0, 0, 0);
                acc2 = MFMA_B16(A2, B2, acc2, 0, 0, 0);
                acc2 = MFMA_B16(A3, B3, acc2, 0, 0, 0);
            }
        }

        // ---- extract: D col = lane&15 (q in tile), D row = grp*4+pp (w) ----
#pragma unroll
        for (int d = 0; d < 3; ++d) {
            const bool dok = (d == 0) ? dok0 : ((d == 1) ? true : dok2);
            const f32x4 ac = (d == 0) ? acc0 : ((d == 1) ? acc1 : acc2);
            const float t2 = (d == 0) ? t20 : ((d == 1) ? t21 : t22);
#pragma unroll
            for (int pp = 0; pp < 4; ++pp) {
                const int wl = grp * 4 + pp;
                const int j  = 16 * (d - 1) + col - wl + 4;
                if ((unsigned)j < 9u) {
                    float val = 0.f;
                    if (rok && dok) {
                        float cs = r2v[pp] + t2 - 2.f * ac[pp];
                        val = __builtin_amdgcn_sqrtf(fmaxf(cs, 0.f));
                    }
                    ldsx[wv][wl][j] = val;   // within-wave use only
                }
            }
        }

        float* ob = outb0 + (size_t)(i * 9) * TPLANE;
        const float v0 = ldsx[wv][col][grp];
        const float v1 = ldsx[wv][col][4 + grp];
        ob[(size_t)grp * TPLANE + col] = v0;            // j=grp
        ob[(size_t)(4 + grp) * TPLANE + col] = v1;      // j=4+grp
        if (lane < 16) ob[(size_t)8 * TPLANE + col] = ldsx[wv][col][8];  // j=8
    }
}

// ---------------- Fallback (round-3 kernel, used if ws too small) ----------
__global__ __launch_bounds__(256, 4)
void corrcost3(const float* __restrict__ ref,
               const float* __restrict__ tgt,
               float* __restrict__ out)
{
    const int tid  = threadIdx.x;
    const int lane = tid & 63;
    const int wv   = tid >> 6;
    const int bid = blockIdx.x;
    const int swz = (bid & 7) * 1296 + (bid >> 3);
    const int u   = swz * 4 + wv;
    const int i   = u % 9;
    const int v9  = u / 9;
    const int wt  = v9 % 12;
    const int v12 = v9 / 12;
    const int h   = v12 % 96;
    const int b   = v12 / 96;
    const int w0  = wt * 16;
    const int q0  = w0 - 8;
    const int row = h + i - 4;
    const bool rok = (unsigned)row < (unsigned)H_N;

    const float* ref_b = ref + (size_t)b * CPLANE;
    const float* tgt_b = tgt + (size_t)b * CPLANE;
    float* out_b = out + (size_t)b * 81 * TPLANE;
    const int col = lane & 15;
    const int ke  = (lane >> 4) * 8;

    s16x8 A[4];
    float r2p = 0.f;
    const float* aptr = ref_b + (size_t)ke * TPLANE + h * W_N + w0 + col;
#pragma unroll
    for (int kc = 0; kc < 4; ++kc) {
#pragma unroll
        for (int e = 0; e < 8; ++e) {
            float v = aptr[(size_t)(kc * 32 + e) * TPLANE];
            short s = f2bf(v);
            float vb = bf2f(s);
            r2p = fmaf(vb, vb, r2p);
            A[kc][e] = s;
        }
    }
    r2p += __shfl_xor(r2p, 16);
    r2p += __shfl_xor(r2p, 32);
    float r2r[4];
#pragma unroll
    for (int pp = 0; pp < 4; ++pp)
        r2r[pp] = __shfl(r2p, (lane >> 4) * 4 + pp);

    f32x4 acc0 = {0.f, 0.f, 0.f, 0.f}, acc1 = acc0;
    float t20 = 0.f, t21 = 0.f;
    if (rok) {
        const float* bbase = tgt_b + (size_t)ke * TPLANE + (size_t)row * W_N;
#pragma unroll
        for (int t = 0; t < 2; ++t) {
            const int q = q0 + t * 16 + col;
            const bool qok = (unsigned)q < (unsigned)W_N;
            const float* bptr = bbase + q;
            s16x8 Bf[4];
            float t2p = 0.f;
#pragma unroll
            for (int kc = 0; kc < 4; ++kc) {
#pragma unroll
                for (int e = 0; e < 8; ++e) {
                    float v = qok ? bptr[(size_t)(kc * 32 + e) * TPLANE] : 0.f;
                    short s = f2bf(v);
                    float vb = bf2f(s);
                    t2p = fmaf(vb, vb, t2p);
                    Bf[kc][e] = s;
                }
            }
            t2p += __shfl_xor(t2p, 16);
            t2p += __shfl_xor(t2p, 32);
            if (t == 0) {
                t20 = t2p;
#pragma unroll
                for (int kc = 0; kc < 4; ++kc)
                    acc0 = MFMA_B16(A[kc], Bf[kc], acc0, 0, 0, 0);
            } else {
                t21 = t2p;
#pragma unroll
                for (int kc = 0; kc < 4; ++kc)
                    acc1 = MFMA_B16(A[kc], Bf[kc], acc1, 0, 0, 0);
            }
        }
    }
#pragma unroll
    for (int t = 0; t < 2; ++t) {
        const int q = q0 + t * 16 + col;
        const bool qok = (unsigned)q < (unsigned)W_N;
        const f32x4 a = t ? acc1 : acc0;
        const float t2 = t ? t21 : t20;
#pragma unroll
        for (int pp = 0; pp < 4; ++pp) {
            const int wl = (lane >> 4) * 4 + pp;
            const int j  = q - (w0 + wl) + 4;
            if ((unsigned)j < 9u) {
                float val = 0.f;
                if (rok && qok) {
                    float cs = r2r[pp] + t2 - 2.f * a[pp];
                    val = cs > 0.f ? sqrtf(cs) : 0.f;
                }
                out_b[(size_t)(i * 9 + j) * TPLANE + h * W_N + w0 + wl] = val;
            }
        }
    }
}

extern "C" void kernel_launch(void* const* d_in, const int* in_sizes, int n_in,
                              void* d_out, int out_size, void* d_ws, size_t ws_size,
                              hipStream_t stream) {
    const float* ref = (const float*)d_in[0];
    const float* tgt = (const float*)d_in[1];
    float* out = (float*)d_out;

    if (ws_size >= WS_NEED && d_ws != nullptr) {
        unsigned char* ws = (unsigned char*)d_ws;
        convert_frag<<<dim3(3 * H_N * B_N, 2), dim3(256), 0, stream>>>(ref, tgt, ws);
        corrcost12<<<dim3(768), dim3(384), 0, stream>>>(ws, out);
    } else {
        corrcost3<<<dim3(10368), dim3(256), 0, stream>>>(ref, tgt, out);
    }
}

// Round 13
// 52.365 us; speedup vs baseline: 1.2422x; 1.2422x over previous
//
#include <hip/hip_runtime.h>

// DifferenceCost, two-pass, fragment-major workspace:
//  Pass A: fp32 [b][c][h][w] -> bf16 MFMA-fragment layout
//          frag[b][row][qtile(12)][kc(4)][lane(64)] (16B per lane), plus
//          per-pixel sum-of-squares planes R2/T2 (on bf16-rounded values).
//  Pass B (corrcost13): wave = (b, h, wt-PAIR, ig). Barrier-free. Each wave:
//          2 A-tiles (reused over 3 rows), per row one 4-qtile B union
//          (16KB, serves both output tiles), 24 MFMAs. L2 traffic 553MB
//          (vs 1.19GB in R11) -> L2-roofline ~15us. cost=sqrt(max(R2+T2-2X,0)).
// Falls back to round-3 single-kernel path if ws too small.

#define B_N 4
#define C_N 128
#define H_N 96
#define W_N 192
#define TPLANE (H_N * W_N)                 // 18432
#define CPLANE ((size_t)C_N * TPLANE)

#define FRAG_ROW_SZ ((size_t)12 * 4 * 1024)          // 49152 B per (b,row)
#define BF_SZ   ((size_t)B_N * H_N * FRAG_ROW_SZ)    // 18,874,368
#define REFF_OFF ((size_t)0)
#define TGTF_OFF BF_SZ
#define SQ_SZ   ((size_t)B_N * TPLANE * 4)
#define R2_OFF  (2 * BF_SZ)
#define T2_OFF  (R2_OFF + SQ_SZ)
#define WS_NEED (T2_OFF + SQ_SZ)                     // 38,338,560 B

using f32x4 = __attribute__((ext_vector_type(4))) float;
using s16x8 = __attribute__((ext_vector_type(8))) short;

__device__ __forceinline__ short f2bf(float x) {
    unsigned u = __builtin_bit_cast(unsigned, x);
    u = (u + 0x7fffu + ((u >> 16) & 1u)) >> 16;   // RNE; inputs finite
    return (short)(unsigned short)u;
}
__device__ __forceinline__ float bf2f(short s) {
    return __builtin_bit_cast(float, ((unsigned)(unsigned short)s) << 16);
}

// ---------------- Pass A: convert + fragment-major store + squared sums ----
__global__ __launch_bounds__(256, 4)
void convert_frag(const float* __restrict__ ref, const float* __restrict__ tgt,
                  unsigned char* __restrict__ ws)
{
    __shared__ unsigned int l32[64][65];   // [w][c-pair], stride 65 -> no conflicts

    const int tid = threadIdx.x;
    // bijective XCD chunk swizzle; XCD x owns (b*96+h) in [x*48,(x+1)*48)
    const int bid = blockIdx.x;
    const int u2  = (bid & 7) * 144 + (bid >> 3);   // 1152 = 8 x 144
    const int wc  = u2 % 3;               // which 64-w chunk
    const int h   = (u2 / 3) % H_N;
    const int b   = u2 / (3 * H_N);
    const int w0  = wc * 64;
    const int isT = blockIdx.y;

    const float* src = (isT ? tgt : ref) + (size_t)b * CPLANE + h * W_N + w0;
    unsigned char* dstF = ws + (isT ? TGTF_OFF : REFF_OFF);
    float* sq = (float*)(ws + (isT ? T2_OFF : R2_OFF));

    // phase 1: coalesced fp32 read, convert, pack pairs into LDS
    const int w  = tid & 63;
    const int cq = tid >> 6;
#pragma unroll
    for (int batch = 0; batch < 16; ++batch) {
        int cp = batch * 4 + cq;
        float v0 = src[(size_t)(2 * cp + 0) * TPLANE + w];
        float v1 = src[(size_t)(2 * cp + 1) * TPLANE + w];
        unsigned u = ((unsigned)(unsigned short)f2bf(v0))
                   | ((unsigned)(unsigned short)f2bf(v1) << 16);
        l32[w][cp] = u;
    }
    __syncthreads();

    // phase 2: fragment-major store; each wave-iter writes 1KB contiguous.
#pragma unroll
    for (int it = 0; it < 4; ++it) {
        int idx   = it * 256 + tid;        // 0..1023
        int lane2 = idx & 63;
        int kc    = (idx >> 6) & 3;
        int qt_l  = idx >> 8;              // 0..3
        int w_l   = qt_l * 16 + (lane2 & 15);
        int cp0   = kc * 16 + (lane2 >> 4) * 4;
        uint4 d = make_uint4(l32[w_l][cp0], l32[w_l][cp0 + 1],
                             l32[w_l][cp0 + 2], l32[w_l][cp0 + 3]);
        int qt = wc * 4 + qt_l;
        size_t off = (((size_t)(b * H_N + h) * 12 + qt) * 4 + kc) * 1024
                   + (size_t)lane2 * 16;
        *(uint4*)(dstF + off) = d;
    }

    // phase 3: per-pixel sum of squares (bf16-rounded)
    const int cs = tid & 15;
#pragma unroll
    for (int pass = 0; pass < 4; ++pass) {
        int wr = pass * 16 + (tid >> 4);
        float s = 0.f;
#pragma unroll
        for (int k2 = 0; k2 < 4; ++k2) {
            unsigned u = l32[wr][cs * 4 + k2];
            float lo = __builtin_bit_cast(float, u << 16);
            float hi = __builtin_bit_cast(float, u & 0xffff0000u);
            s = fmaf(lo, lo, fmaf(hi, hi, s));
        }
        s += __shfl_xor(s, 1); s += __shfl_xor(s, 2);
        s += __shfl_xor(s, 4); s += __shfl_xor(s, 8);
        if (cs == 0) sq[(size_t)(b * TPLANE + h * W_N + w0 + wr)] = s;
    }
}

// ---------------- Pass B: wave=(b,h,wt-pair,ig), barrier-free --------------
#define MFMA_B16 __builtin_amdgcn_mfma_f32_16x16x32_bf16

__global__ __launch_bounds__(256)
void corrcost13(const unsigned char* __restrict__ ws, float* __restrict__ out)
{
    __shared__ float ldsx[4][2][16][12];   // per-wave transpose, 6 KiB

    const int tid  = threadIdx.x;
    const int lane = tid & 63;
    const int wv   = tid >> 6;
    const int col  = lane & 15;
    const int grp  = lane >> 4;

    // 1728 blocks = 8 XCDs x 216 (bijective); XCD bh-range matches pass A
    const int bid = blockIdx.x;
    const int u   = (bid & 7) * 216 + (bid >> 3);
    const int gw  = u * 4 + wv;            // ((b*96+h)*6 + wtp)*3 + ig
    const int ig  = gw % 3;
    const int r3  = gw / 3;
    const int wtp = r3 % 6;
    const int bh  = r3 / 6;
    const int h   = bh % H_N;
    const int b   = bh / H_N;
    const int bT  = b * TPLANE;

    const int wt0 = wtp * 2;               // tiles wt0, wt0+1
    const int w00 = wt0 * 16;
    const bool qv0 = (wt0 >= 1);           // qtile wt0-1 exists
    const bool qv3 = (wt0 <= 9);           // qtile wt0+2 exists

    // A fragments: 2 tiles x 4 kc, fully-coalesced 1KB loads
    const unsigned char* fA = ws + REFF_OFF
        + ((size_t)(b * H_N + h) * 12 + wt0) * 4096 + (size_t)lane * 16;
    const s16x8 A00 = *(const s16x8*)(fA);
    const s16x8 A01 = *(const s16x8*)(fA + 1024);
    const s16x8 A02 = *(const s16x8*)(fA + 2048);
    const s16x8 A03 = *(const s16x8*)(fA + 3072);
    const s16x8 A10 = *(const s16x8*)(fA + 4096);
    const s16x8 A11 = *(const s16x8*)(fA + 5120);
    const s16x8 A12 = *(const s16x8*)(fA + 6144);
    const s16x8 A13 = *(const s16x8*)(fA + 7168);

    const float* r2p = (const float*)(ws + R2_OFF) + bT + h * W_N + w00;
    const f32x4 r2v0 = *(const f32x4*)(r2p + grp * 4);
    const f32x4 r2v1 = *(const f32x4*)(r2p + 16 + grp * 4);

#pragma unroll
    for (int tt = 0; tt < 3; ++tt) {
        const int i   = ig * 3 + tt;
        const int row = h + i - 4;
        const bool rok = (unsigned)row < (unsigned)H_N;   // wave-uniform

        f32x4 a00 = {0.f,0.f,0.f,0.f}, a01 = a00, a02 = a00;
        f32x4 a10 = a00, a11 = a00, a12 = a00;
        float t2q0 = 0.f, t2q1 = 0.f, t2q2 = 0.f, t2q3 = 0.f;

        if (rok) {
            const unsigned char* fB = ws + TGTF_OFF
                + (size_t)(b * H_N + row) * FRAG_ROW_SZ + (size_t)lane * 16;
            const float* t2r = (const float*)(ws + T2_OFF) + bT + row * W_N;

            // 4-qtile B union, batch-issued (independent loads -> ILP)
            s16x8 B00, B01, B02, B03, B10, B11, B12, B13;
            s16x8 B20, B21, B22, B23, B30, B31, B32, B33;
            if (qv0) {
                const unsigned char* p = fB + (size_t)(wt0 - 1) * 4096;
                B00 = *(const s16x8*)(p);
                B01 = *(const s16x8*)(p + 1024);
                B02 = *(const s16x8*)(p + 2048);
                B03 = *(const s16x8*)(p + 3072);
                t2q0 = t2r[(wt0 - 1) * 16 + col];
            }
            {
                const unsigned char* p = fB + (size_t)wt0 * 4096;
                B10 = *(const s16x8*)(p);
                B11 = *(const s16x8*)(p + 1024);
                B12 = *(const s16x8*)(p + 2048);
                B13 = *(const s16x8*)(p + 3072);
                t2q1 = t2r[wt0 * 16 + col];
            }
            {
                const unsigned char* p = fB + (size_t)(wt0 + 1) * 4096;
                B20 = *(const s16x8*)(p);
                B21 = *(const s16x8*)(p + 1024);
                B22 = *(const s16x8*)(p + 2048);
                B23 = *(const s16x8*)(p + 3072);
                t2q2 = t2r[(wt0 + 1) * 16 + col];
            }
            if (qv3) {
                const unsigned char* p = fB + (size_t)(wt0 + 2) * 4096;
                B30 = *(const s16x8*)(p);
                B31 = *(const s16x8*)(p + 1024);
                B32 = *(const s16x8*)(p + 2048);
                B33 = *(const s16x8*)(p + 3072);
                t2q3 = t2r[(wt0 + 2) * 16 + col];
            }

            // tile 0: d=0 -> Bq0, d=1 -> Bq1, d=2 -> Bq2
            if (qv0) {
                a00 = MFMA_B16(A00, B00, a00, 0, 0, 0);
                a00 = MFMA_B16(A01, B01, a00, 0, 0, 0);
                a00 = MFMA_B16(A02, B02, a00, 0, 0, 0);
                a00 = MFMA_B16(A03, B03, a00, 0, 0, 0);
            }
            a01 = MFMA_B16(A00, B10, a01, 0, 0, 0);
            a01 = MFMA_B16(A01, B11, a01, 0, 0, 0);
            a01 = MFMA_B16(A02, B12, a01, 0, 0, 0);
            a01 = MFMA_B16(A03, B13, a01, 0, 0, 0);
            a02 = MFMA_B16(A00, B20, a02, 0, 0, 0);
            a02 = MFMA_B16(A01, B21, a02, 0, 0, 0);
            a02 = MFMA_B16(A02, B22, a02, 0, 0, 0);
            a02 = MFMA_B16(A03, B23, a02, 0, 0, 0);
            // tile 1: d=0 -> Bq1, d=1 -> Bq2, d=2 -> Bq3
            a10 = MFMA_B16(A10, B10, a10, 0, 0, 0);
            a10 = MFMA_B16(A11, B11, a10, 0, 0, 0);
            a10 = MFMA_B16(A12, B12, a10, 0, 0, 0);
            a10 = MFMA_B16(A13, B13, a10, 0, 0, 0);
            a11 = MFMA_B16(A10, B20, a11, 0, 0, 0);
            a11 = MFMA_B16(A11, B21, a11, 0, 0, 0);
            a11 = MFMA_B16(A12, B22, a11, 0, 0, 0);
            a11 = MFMA_B16(A13, B23, a11, 0, 0, 0);
            if (qv3) {
                a12 = MFMA_B16(A10, B30, a12, 0, 0, 0);
                a12 = MFMA_B16(A11, B31, a12, 0, 0, 0);
                a12 = MFMA_B16(A12, B32, a12, 0, 0, 0);
                a12 = MFMA_B16(A13, B33, a12, 0, 0, 0);
            }
        }

        // ---- extract both tiles: D col = q-in-tile, D row = grp*4+pp ----
#pragma unroll
        for (int m = 0; m < 2; ++m) {
            const f32x4 r2v = m ? r2v1 : r2v0;
#pragma unroll
            for (int d = 0; d < 3; ++d) {
                const bool dok = (m == 0 && d == 0) ? qv0
                               : (m == 1 && d == 2) ? qv3 : true;
                const f32x4 ac = (m == 0)
                    ? ((d == 0) ? a00 : (d == 1) ? a01 : a02)
                    : ((d == 0) ? a10 : (d == 1) ? a11 : a12);
                const float t2 = ((m + d) == 0) ? t2q0 : ((m + d) == 1) ? t2q1
                               : ((m + d) == 2) ? t2q2 : t2q3;
#pragma unroll
                for (int pp = 0; pp < 4; ++pp) {
                    const int wl = grp * 4 + pp;
                    const int j  = 16 * (d - 1) + col - wl + 4;
                    if ((unsigned)j < 9u) {
                        float val = 0.f;
                        if (rok && dok) {
                            float cs = r2v[pp] + t2 - 2.f * ac[pp];
                            val = __builtin_amdgcn_sqrtf(fmaxf(cs, 0.f));
                        }
                        ldsx[wv][m][wl][j] = val;   // within-wave only
                    }
                }
            }
        }

#pragma unroll
        for (int m = 0; m < 2; ++m) {
            float* ob = out + (size_t)(b * 81 + i * 9) * TPLANE + h * W_N
                      + (wt0 + m) * 16;
            const float v0 = ldsx[wv][m][col][grp];
            const float v1 = ldsx[wv][m][col][4 + grp];
            ob[(size_t)grp * TPLANE + col] = v0;            // j=grp
            ob[(size_t)(4 + grp) * TPLANE + col] = v1;      // j=4+grp
            if (lane < 16) ob[(size_t)8 * TPLANE + col] = ldsx[wv][m][col][8];
        }
    }
}

// ---------------- Fallback (round-3 kernel, used if ws too small) ----------
__global__ __launch_bounds__(256, 4)
void corrcost3(const float* __restrict__ ref,
               const float* __restrict__ tgt,
               float* __restrict__ out)
{
    const int tid  = threadIdx.x;
    const int lane = tid & 63;
    const int wv   = tid >> 6;
    const int bid = blockIdx.x;
    const int swz = (bid & 7) * 1296 + (bid >> 3);
    const int u   = swz * 4 + wv;
    const int i   = u % 9;
    const int v9  = u / 9;
    const int wt  = v9 % 12;
    const int v12 = v9 / 12;
    const int h   = v12 % 96;
    const int b   = v12 / 96;
    const int w0  = wt * 16;
    const int q0  = w0 - 8;
    const int row = h + i - 4;
    const bool rok = (unsigned)row < (unsigned)H_N;

    const float* ref_b = ref + (size_t)b * CPLANE;
    const float* tgt_b = tgt + (size_t)b * CPLANE;
    float* out_b = out + (size_t)b * 81 * TPLANE;
    const int col = lane & 15;
    const int ke  = (lane >> 4) * 8;

    s16x8 A[4];
    float r2p = 0.f;
    const float* aptr = ref_b + (size_t)ke * TPLANE + h * W_N + w0 + col;
#pragma unroll
    for (int kc = 0; kc < 4; ++kc) {
#pragma unroll
        for (int e = 0; e < 8; ++e) {
            float v = aptr[(size_t)(kc * 32 + e) * TPLANE];
            short s = f2bf(v);
            float vb = bf2f(s);
            r2p = fmaf(vb, vb, r2p);
            A[kc][e] = s;
        }
    }
    r2p += __shfl_xor(r2p, 16);
    r2p += __shfl_xor(r2p, 32);
    float r2r[4];
#pragma unroll
    for (int pp = 0; pp < 4; ++pp)
        r2r[pp] = __shfl(r2p, (lane >> 4) * 4 + pp);

    f32x4 acc0 = {0.f, 0.f, 0.f, 0.f}, acc1 = acc0;
    float t20 = 0.f, t21 = 0.f;
    if (rok) {
        const float* bbase = tgt_b + (size_t)ke * TPLANE + (size_t)row * W_N;
#pragma unroll
        for (int t = 0; t < 2; ++t) {
            const int q = q0 + t * 16 + col;
            const bool qok = (unsigned)q < (unsigned)W_N;
            const float* bptr = bbase + q;
            s16x8 Bf[4];
            float t2p = 0.f;
#pragma unroll
            for (int kc = 0; kc < 4; ++kc) {
#pragma unroll
                for (int e = 0; e < 8; ++e) {
                    float v = qok ? bptr[(size_t)(kc * 32 + e) * TPLANE] : 0.f;
                    short s = f2bf(v);
                    float vb = bf2f(s);
                    t2p = fmaf(vb, vb, t2p);
                    Bf[kc][e] = s;
                }
            }
            t2p += __shfl_xor(t2p, 16);
            t2p += __shfl_xor(t2p, 32);
            if (t == 0) {
                t20 = t2p;
#pragma unroll
                for (int kc = 0; kc < 4; ++kc)
                    acc0 = MFMA_B16(A[kc], Bf[kc], acc0, 0, 0, 0);
            } else {
                t21 = t2p;
#pragma unroll
                for (int kc = 0; kc < 4; ++kc)
                    acc1 = MFMA_B16(A[kc], Bf[kc], acc1, 0, 0, 0);
            }
        }
    }
#pragma unroll
    for (int t = 0; t < 2; ++t) {
        const int q = q0 + t * 16 + col;
        const bool qok = (unsigned)q < (unsigned)W_N;
        const f32x4 a = t ? acc1 : acc0;
        const float t2 = t ? t21 : t20;
#pragma unroll
        for (int pp = 0; pp < 4; ++pp) {
            const int wl = (lane >> 4) * 4 + pp;
            const int j  = q - (w0 + wl) + 4;
            if ((unsigned)j < 9u) {
                float val = 0.f;
                if (rok && qok) {
                    float cs = r2r[pp] + t2 - 2.f * a[pp];
                    val = cs > 0.f ? sqrtf(cs) : 0.f;
                }
                out_b[(size_t)(i * 9 + j) * TPLANE + h * W_N + w0 + wl] = val;
            }
        }
    }
}

extern "C" void kernel_launch(void* const* d_in, const int* in_sizes, int n_in,
                              void* d_out, int out_size, void* d_ws, size_t ws_size,
                              hipStream_t stream) {
    const float* ref = (const float*)d_in[0];
    const float* tgt = (const float*)d_in[1];
    float* out = (float*)d_out;

    if (ws_size >= WS_NEED && d_ws != nullptr) {
        unsigned char* ws = (unsigned char*)d_ws;
        convert_frag<<<dim3(3 * H_N * B_N, 2), dim3(256), 0, stream>>>(ref, tgt, ws);
        corrcost13<<<dim3(1728), dim3(256), 0, stream>>>(ws, out);
    } else {
        corrcost3<<<dim3(10368), dim3(256), 0, stream>>>(ref, tgt, out);
    }
}